// Round 17
// baseline (128.725 us; speedup 1.0000x reference)
//
#include <hip/hip_runtime.h>

#define PEPS  1e-5f
#define LOG2E 1.4426950408889634f

__device__ __forceinline__ float fast_rcp(float x) { return __builtin_amdgcn_rcpf(x); }

// Pair-shared sigmoid blend: one v_rcp per two elements (trans-pipe relief).
__device__ __forceinline__ void patch_pair(float& x, float& y, float nrs2, float mrs) {
    const float tx = fminf(fmaf(x, nrs2, mrs), 60.0f);
    const float ty = fminf(fmaf(y, nrs2, mrs), 60.0f);
    const float ex = __builtin_amdgcn_exp2f(tx);
    const float ey = __builtin_amdgcn_exp2f(ty);
    const float ax = 1.0f + ex;
    const float ay = 1.0f + ey;
    const float r  = fast_rcp(ax * ay);
    x = x * fmaf(0.5f, r * ay, 0.5f);
    y = y * fmaf(0.5f, r * ax, 0.5f);
}

__device__ __forceinline__ void patch_quad(float4& t, float nrs2, float mrs) {
    patch_pair(t.x, t.y, nrs2, mrs);
    patch_pair(t.z, t.w, nrs2, mrs);
}

__device__ __forceinline__ void wave_reduce2(float& a, float& b) {
#pragma unroll
    for (int off = 32; off; off >>= 1) {
        a += __shfl_xor(a, off);
        b += __shfl_xor(b, off);
    }
}

// async global->LDS, 16 B per lane (LDS dest wave-uniform base, src per-lane).
__device__ __forceinline__ void gld_lds16(const float* g, float* l) {
    __builtin_amdgcn_global_load_lds(
        (const __attribute__((address_space(1))) void*)g,
        (__attribute__((address_space(3))) void*)l, 16, 0, 0);
}

// r14 champion (113.0us) with ONE structural change: 2-DEEP PREFETCH via
// double-buffered 64 KiB quarter-tiles.
// Champion timeline model (closes to 27.8 vs 28.3us/image measured):
//   A-wait 5.3us (prefetch issued at E(k-1) has only F..H ~7us to drain 5.3us
//   behind 10.7us of stores -> zero slack, A always stalls) + B 10.7 +
//   C/D 4.5 HBM-IDLE (loads consumed, prefetch not yet issued, stores not
//   ready) + E..G covered + H 2.
// Fix: tileQ[2] of 64 image-rows each; prefetch img k+1 issued at A(k) — a
// full ~25us before its A(k+1) deadline — into the buffer B(k-1) freed.
// Waves 0-3 read their whole patch from LDS; waves 4-15 direct-global
// (192 KiB in B, which also covers C/D).
// vmcnt at A(k): per-wave FIFO = [4 prefetch(k), oldest] + [16 stores(k-1)]
// -> vmcnt(16) retires exactly the prefetch; k=0 drains fully.
// Races: prefetch writes tile[(k+1)&1], B reads tile[k&1] — disjoint.
// Failure signatures: spill -> VGPR=64/SGPR=112/WRITE>280MB; absmax blowup ->
// rotation bug; null -> queue-ordering-bound, try nt stores or declare.
__global__ __launch_bounds__(1024) void fused_pyramid_pipe9(
    const float* __restrict__ in, float* __restrict__ out)
{
    constexpr int W   = 256;
    constexpr int IMG = W * W;                  // 65536 floats
    __shared__ float tileQ[2][16384];           // 2 x 64 KiB: rows 0..63 (quarter)
    __shared__ float redS[16], redQ[16];        // pass-2 partials
    __shared__ float redS2[16], redQ2[16];      // pass-3 partials

    const int tid   = threadIdx.x;
    const int wave  = tid >> 6;                 // 0..15 -> 4x4 grid of 64x64 patches
    const int lane  = tid & 63;
    const int pr    = wave >> 2;
    const int pc    = wave & 3;
    const int rlane = lane >> 4;                // 0..3
    const int c4    = lane & 15;
    const int bid   = blockIdx.x;

    // prefetch rows 0..63 of image `src` into tileQ[buf]: 64 rows x 1 KiB,
    // wave handles rows wave*4..wave*4+3 (one gld_lds16 per row).
    auto prefetch_quarter = [&](const float* src, int buf) {
#pragma unroll
        for (int i = 0; i < 4; ++i) {
            const int r = wave * 4 + i;
            gld_lds16(src + r * W + lane * 4, &tileQ[buf][r * W]);
        }
    };

    // ---- prologue: prefetch image bid's quarter into buffer 0 --------------
    prefetch_quarter(in + (size_t)bid * IMG, 0);

    for (int k = 0; k < 4; ++k) {
        const int img = bid + k * 256;
        const float* in_img  = in  + (size_t)img * IMG;
        float*       out_img = out + (size_t)img * IMG;

        // A: wait own prefetch (counted: 4 oldest = this image's quarter;
        //    previous stores keep draining), raw barrier, then IMMEDIATELY
        //    issue next image's prefetch into the other buffer (freed by
        //    B(k-1)) — a full iteration ahead of its deadline.
        if (k == 0) { asm volatile("s_waitcnt vmcnt(0)" ::: "memory"); }
        else        { asm volatile("s_waitcnt vmcnt(16)" ::: "memory"); }
        __builtin_amdgcn_s_barrier();
        __builtin_amdgcn_sched_barrier(0);
        if (k < 3) prefetch_quarter(in + (size_t)(bid + (k + 1) * 256) * IMG, (k + 1) & 1);
        __builtin_amdgcn_sched_barrier(0);

        // B: load v[16] + pass-1 sums. Waves 0-3 (top band) from LDS quarter,
        //    waves 4-15 direct from global.
        float4 v[16];
        float s = 0.f, q = 0.f;
        if (wave < 4) {
            const float* tl = &tileQ[k & 1][pc * 64];
#pragma unroll
            for (int u = 0; u < 16; ++u) {
                const int r = u * 4 + rlane;
                const float4 t = *reinterpret_cast<const float4*>(tl + r * W + c4 * 4);
                v[u] = t;
                s += (t.x + t.y) + (t.z + t.w);
                q = fmaf(t.x, t.x, fmaf(t.y, t.y, fmaf(t.z, t.z, fmaf(t.w, t.w, q))));
            }
        } else {
            const float* gl = in_img + (size_t)(pr * 64) * W + pc * 64;
#pragma unroll
            for (int u = 0; u < 16; ++u) {
                const int r = u * 4 + rlane;
                const float4 t = *reinterpret_cast<const float4*>(gl + (size_t)r * W + c4 * 4);
                v[u] = t;
                s += (t.x + t.y) + (t.z + t.w);
                q = fmaf(t.x, t.x, fmaf(t.y, t.y, fmaf(t.z, t.z, fmaf(t.w, t.w, q))));
            }
        }

        // C: pass 1 (s=64), wave-local
        wave_reduce2(s, q);
        float m  = s * (1.0f / 4096.0f);
        float rs = rsqrtf(fmaf(-m, m, q * (1.0f / 4096.0f)) + PEPS);
        float nrs2 = rs * -LOG2E;
        float mrs  = m * rs * LOG2E;

        float s2 = 0.f, q2 = 0.f;
#pragma unroll
        for (int u = 0; u < 16; ++u) {
            float4 t = v[u];
            patch_quad(t, nrs2, mrs);
            v[u] = t;
            s2 += (t.x + t.y) + (t.z + t.w);
            q2 = fmaf(t.x, t.x, fmaf(t.y, t.y, fmaf(t.z, t.z, fmaf(t.w, t.w, q2))));
        }

        // D: publish pass-2 partials; raw barrier (LDS ordering only —
        //    stores and the new prefetch stay in flight)
        wave_reduce2(s2, q2);
        if (lane == 0) { redS[wave] = s2; redQ[wave] = q2; }
        asm volatile("s_waitcnt lgkmcnt(0)" ::: "memory");
        __builtin_amdgcn_s_barrier();

        // F: pass 2 (s=128): 2x2 wave group
        const int w00 = wave & ~5;
        {
            const float S = (redS[w00] + redS[w00 + 1]) + (redS[w00 + 4] + redS[w00 + 5]);
            const float Q = (redQ[w00] + redQ[w00 + 1]) + (redQ[w00 + 4] + redQ[w00 + 5]);
            m  = S * (1.0f / 16384.0f);
            rs = rsqrtf(fmaf(-m, m, Q * (1.0f / 16384.0f)) + PEPS);
        }
        nrs2 = rs * -LOG2E;
        mrs  = m * rs * LOG2E;

        float s3 = 0.f, q3 = 0.f;
#pragma unroll
        for (int u = 0; u < 16; ++u) {
            float4 t = v[u];
            patch_quad(t, nrs2, mrs);
            v[u] = t;
            s3 += (t.x + t.y) + (t.z + t.w);
            q3 = fmaf(t.x, t.x, fmaf(t.y, t.y, fmaf(t.z, t.z, fmaf(t.w, t.w, q3))));
        }

        // G: pass 3 (s=256): publish partials; raw barrier (no vmcnt drain)
        wave_reduce2(s3, q3);
        if (lane == 0) { redS2[wave] = s3; redQ2[wave] = q3; }
        asm volatile("s_waitcnt lgkmcnt(0)" ::: "memory");
        __builtin_amdgcn_s_barrier();
        __builtin_amdgcn_sched_barrier(0);
        {
            float S = 0.f, Q = 0.f;
#pragma unroll
            for (int w = 0; w < 16; ++w) { S += redS2[w]; Q += redQ2[w]; }
            m  = S * (1.0f / 65536.0f);
            rs = rsqrtf(fmaf(-m, m, Q * (1.0f / 65536.0f)) + PEPS);
        }
        nrs2 = rs * -LOG2E;
        mrs  = m * rs * LOG2E;

        // H: apply pass 3 + store
        {
            float* go = out_img + (size_t)(pr * 64) * W + pc * 64;
#pragma unroll
            for (int u = 0; u < 16; ++u) {
                const int r = u * 4 + rlane;
                float4 t = v[u];
                patch_quad(t, nrs2, mrs);
                *reinterpret_cast<float4*>(go + (size_t)r * W + c4 * 4) = t;
            }
        }
    }
}

extern "C" void kernel_launch(void* const* d_in, const int* in_sizes, int n_in,
                              void* d_out, int out_size, void* d_ws, size_t ws_size,
                              hipStream_t stream)
{
    const float* x = (const float*)d_in[0];
    float* out = (float*)d_out;
    // 1024 images, 256 persistent blocks x 4 images each; no workspace needed.
    fused_pyramid_pipe9<<<256, 1024, 0, stream>>>(x, out);
}